// Round 5
// baseline (490.781 us; speedup 1.0000x reference)
//
#include <hip/hip_runtime.h>
#include <hip/hip_bf16.h>
#include <cstdint>

#define BB 64
#define TN 2048
#define RNN 1024
#define EMB 512
#define ATT 128
#define NF 32
#define KS 31
#define PADK 15
#define CKN 62    // 2*KS
#define ETT 256   // t-tile per fused block
#define CHK 32    // t-chunk: energies burst then stream burst
#define NTILE (TN / ETT)   // 8

__device__ __forceinline__ float fast_rcp(float x) {
#if __has_builtin(__builtin_amdgcn_rcpf)
    return __builtin_amdgcn_rcpf(x);
#else
    return 1.0f / x;
#endif
}

// tanh(x) = 1 - 2/(exp(2x)+1)
__device__ __forceinline__ float fast_tanh(float x) {
    float s = __expf(2.0f * x);
    return 1.0f - 2.0f * fast_rcp(s + 1.0f);
}

// blocks 0..BB-1: pq[b][a] = dot(hidden[b], Wq[a])
// block BB:       UT[ck][a] = sum_f Wd[a][f] * conv_w[f][ck]  (transposed)
__global__ __launch_bounds__(256) void prep_kernel(
    const float* __restrict__ ahs, const float* __restrict__ Wq,
    const float* __restrict__ conv_w, const float* __restrict__ Wd,
    float* __restrict__ ws_pq, float* __restrict__ ws_UT)
{
    int tid = threadIdx.x;
    if (blockIdx.x < BB) {
        int b = blockIdx.x;
        __shared__ float sh[RNN];
        for (int i = tid; i < RNN; i += 256) sh[i] = ahs[b * RNN + i];
        __syncthreads();
        int a = tid & 127, half = tid >> 7;
        const float4* wq4 = (const float4*)(Wq + a * RNN + half * (RNN / 2));
        const float4* sh4 = (const float4*)(sh + half * (RNN / 2));
        float acc = 0.0f;
#pragma unroll 8
        for (int i = 0; i < RNN / 8; ++i) {
            float4 w4 = wq4[i]; float4 h4 = sh4[i];
            acc = fmaf(w4.x, h4.x, acc);
            acc = fmaf(w4.y, h4.y, acc);
            acc = fmaf(w4.z, h4.z, acc);
            acc = fmaf(w4.w, h4.w, acc);
        }
        __shared__ float part[256];
        part[tid] = acc;
        __syncthreads();
        if (half == 0) ws_pq[b * ATT + a] = part[a] + part[a + 128];
    } else {
        __shared__ float sWd[ATT * NF];
        __shared__ float sCw[NF * CKN];
        for (int i = tid; i < ATT * NF; i += 256) sWd[i] = Wd[i];
        for (int i = tid; i < NF * CKN; i += 256) sCw[i] = conv_w[i];
        __syncthreads();
        for (int idx = tid; idx < ATT * CKN; idx += 256) {
            int a = idx & 127, ck = idx >> 7;
            float acc = 0.0f;
#pragma unroll
            for (int f = 0; f < NF; ++f) acc = fmaf(sWd[a * NF + f], sCw[f * CKN + ck], acc);
            ws_UT[idx] = acc;
        }
    }
}

// grid (BB, NTILE), block 256 = 4 waves.
// Per 32-t chunk: [energies burst: wave (h=w&1, seg=w>>1), lane=a-half] then
// [online-softmax update + context stream burst] -> HBM/VALU interleave.
__global__ __launch_bounds__(256) void fused_kernel(
    const float* __restrict__ awc, const float* __restrict__ pm,
    const float* __restrict__ vvec, const uint8_t* __restrict__ mask,
    const float* __restrict__ mem,
    const float* __restrict__ ws_pq, const float* __restrict__ ws_UT,
    float* __restrict__ ws_e, float* __restrict__ ws_mt,
    float* __restrict__ ws_st, float* __restrict__ ws_cpart)
{
    __shared__ __align__(16) float sA[2][ETT + 32];  // conv input + 15-halo
    __shared__ float sEc[2][CHK];                    // per-a-half partial e
    __shared__ float sEsum[CHK];                     // combined (masked) e
    __shared__ float4 sacc[128];

    int tid = threadIdx.x;
    int b = blockIdx.x, tile = blockIdx.y, t0 = tile * ETT;

    for (int idx = tid; idx < 2 * (ETT + 30); idx += 256) {
        int c = idx / (ETT + 30), tt = idx % (ETT + 30);
        int t = t0 + tt - PADK;
        sA[c][tt] = (t >= 0 && t < TN) ? awc[(b * 2 + c) * TN + t] : 0.0f;
    }

    int lane = tid & 63, w = tid >> 6;
    int h = w & 1, seg = w >> 1;
    int a = h * 64 + lane;

    float U[CKN];
#pragma unroll
    for (int k = 0; k < CKN; ++k) U[k] = ws_UT[k * ATT + a];   // coalesced
    float q = ws_pq[b * ATT + a];
    float vv = vvec[a];
    const float* pmb = pm + (size_t)b * TN * ATT + a;
    const float4* m4 = (const float4*)(mem + (size_t)(b * TN + t0) * EMB);
    int e4 = tid & 127, sub = tid >> 7;

    float m_run = -1e30f, s_run = 0.0f;
    float4 acc = make_float4(0.f, 0.f, 0.f, 0.f);
    __syncthreads();

    for (int c = 0; c < ETT / CHK; ++c) {
        int cb = c * CHK;
        // ---- energies for this chunk: each wave does 16 t's (4 groups of 4)
#pragma unroll
        for (int g = 0; g < 4; ++g) {
            int tl = cb + seg * 16 + g * 4;
            const float4* a0 = (const float4*)(&sA[0][tl]);   // tl % 4 == 0
            const float4* a1 = (const float4*)(&sA[1][tl]);
            float x0[36], x1[36];
#pragma unroll
            for (int j = 0; j < 9; ++j) {              // ds_read_b128 x18
                float4 r0 = a0[j], r1 = a1[j];
                x0[4 * j] = r0.x; x0[4 * j + 1] = r0.y; x0[4 * j + 2] = r0.z; x0[4 * j + 3] = r0.w;
                x1[4 * j] = r1.x; x1[4 * j + 1] = r1.y; x1[4 * j + 2] = r1.z; x1[4 * j + 3] = r1.w;
            }
            float p[4];
#pragma unroll
            for (int u = 0; u < 4; ++u) p[u] = pmb[(size_t)(t0 + tl + u) * ATT];
#pragma unroll
            for (int u = 0; u < 4; ++u) {
                float lo = 0.0f;
#pragma unroll
                for (int k = 0; k < KS; ++k) {
                    lo = fmaf(U[k],      x0[u + k], lo);
                    lo = fmaf(U[KS + k], x1[u + k], lo);
                }
                float e = vv * fast_tanh(q + lo + p[u]);
#pragma unroll
                for (int off = 32; off >= 1; off >>= 1) e += __shfl_xor(e, off, 64);
                if (lane == 0) sEc[h][seg * 16 + g * 4 + u] = e;
            }
        }
        __syncthreads();
        if (tid < CHK) {
            float e = sEc[0][tid] + sEc[1][tid];
            if (mask[(size_t)b * TN + t0 + cb + tid]) e = -1e30f;
            sEsum[tid] = e;
            ws_e[(size_t)b * TN + t0 + cb + tid] = e;
        }
        __syncthreads();
        // ---- online softmax stats (redundant identical per thread)
        float m_new = m_run;
#pragma unroll
        for (int i = 0; i < CHK; ++i) m_new = fmaxf(m_new, sEsum[i]);
        float scl = __expf(m_run - m_new);
        float s_add = 0.0f;
#pragma unroll
        for (int i = 0; i < CHK; ++i) s_add += __expf(sEsum[i] - m_new);
        s_run = fmaf(s_run, scl, s_add);
        acc.x *= scl; acc.y *= scl; acc.z *= scl; acc.w *= scl;
        m_run = m_new;
        // ---- context stream burst: 32 rows, this thread covers rows == sub (mod 2)
        for (int i = sub; i < CHK; i += 2) {
            float wt = __expf(sEsum[i] - m_new);
            float4 mv = m4[(size_t)(cb + i) * 128 + e4];
            acc.x = fmaf(wt, mv.x, acc.x);
            acc.y = fmaf(wt, mv.y, acc.y);
            acc.z = fmaf(wt, mv.z, acc.z);
            acc.w = fmaf(wt, mv.w, acc.w);
        }
        __syncthreads();
    }

    if (sub == 1) sacc[e4] = acc;
    __syncthreads();
    if (sub == 0) {
        float4 o = sacc[e4];
        acc.x += o.x; acc.y += o.y; acc.z += o.z; acc.w += o.w;
        ((float4*)&ws_cpart[((size_t)tile * BB + b) * EMB])[e4] = acc;
        if (tid == 0) {
            ws_mt[tile * BB + b] = m_run;
            ws_st[tile * BB + b] = s_run;
        }
    }
}

// grid BB: global (m, S) per row from 8 tile stats; weights from ws_e.
__global__ __launch_bounds__(256) void weights_kernel(
    const float* __restrict__ ws_e, const float* __restrict__ ws_mt,
    const float* __restrict__ ws_st, float* __restrict__ out_w)
{
    int b = blockIdx.x, tid = threadIdx.x;
    float m = -1e30f;
#pragma unroll
    for (int t = 0; t < NTILE; ++t) m = fmaxf(m, ws_mt[t * BB + b]);
    float S = 0.0f;
#pragma unroll
    for (int t = 0; t < NTILE; ++t) S += ws_st[t * BB + b] * __expf(ws_mt[t * BB + b] - m);
    float inv = 1.0f / S;
#pragma unroll
    for (int i = 0; i < TN / 256; ++i) {
        int t = tid + i * 256;
        out_w[(size_t)b * TN + t] = __expf(ws_e[(size_t)b * TN + t] - m) * inv;
    }
}

// grid (BB*EMB/256): combine tile partials with rescale, normalize.
__global__ __launch_bounds__(256) void ctx_reduce_kernel(
    const float* __restrict__ ws_cpart, const float* __restrict__ ws_mt,
    const float* __restrict__ ws_st, float* __restrict__ out_ctx)
{
    int o = blockIdx.x * 256 + threadIdx.x;
    int b = o >> 9, e = o & 511;
    float m = -1e30f;
#pragma unroll
    for (int t = 0; t < NTILE; ++t) m = fmaxf(m, ws_mt[t * BB + b]);
    float S = 0.0f, acc = 0.0f;
#pragma unroll
    for (int t = 0; t < NTILE; ++t) {
        float f = __expf(ws_mt[t * BB + b] - m);
        S += ws_st[t * BB + b] * f;
        acc += ws_cpart[((size_t)t * BB + b) * EMB + e] * f;
    }
    out_ctx[o] = acc / S;
}

extern "C" void kernel_launch(void* const* d_in, const int* in_sizes, int n_in,
                              void* d_out, int out_size, void* d_ws, size_t ws_size,
                              hipStream_t stream) {
    const float*   ahs  = (const float*)d_in[0];
    const float*   mem  = (const float*)d_in[1];
    const float*   pm   = (const float*)d_in[2];
    const float*   awc  = (const float*)d_in[3];
    const uint8_t* mask = (const uint8_t*)d_in[4];
    const float*   Wq   = (const float*)d_in[5];
    const float*   cw   = (const float*)d_in[6];
    const float*   Wd   = (const float*)d_in[7];
    const float*   v    = (const float*)d_in[8];

    float* out_ctx = (float*)d_out;             // B*EMB
    float* out_w   = (float*)d_out + BB * EMB;  // B*T

    float* ws       = (float*)d_ws;
    float* ws_pq    = ws;             // 8192 floats
    float* ws_UT    = ws + 8192;      // 7936 floats
    float* ws_e     = ws + 16384;     // 131072 floats
    float* ws_mt    = ws + 147456;    // 512 floats
    float* ws_st    = ws + 147968;    // 512 floats
    float* ws_cpart = ws + 148480;    // NTILE*BB*EMB = 262144 floats

    prep_kernel<<<BB + 1, 256, 0, stream>>>(ahs, Wq, cw, Wd, ws_pq, ws_UT);
    fused_kernel<<<dim3(BB, NTILE), 256, 0, stream>>>(
        awc, pm, v, mask, mem, ws_pq, ws_UT, ws_e, ws_mt, ws_st, ws_cpart);
    weights_kernel<<<BB, 256, 0, stream>>>(ws_e, ws_mt, ws_st, out_w);
    ctx_reduce_kernel<<<(BB * EMB) / 256, 256, 0, stream>>>(ws_cpart, ws_mt, ws_st, out_ctx);
}

// Round 6
// 467.440 us; speedup vs baseline: 1.0499x; 1.0499x over previous
//
#include <hip/hip_runtime.h>
#include <hip/hip_bf16.h>
#include <cstdint>

#define BB 64
#define TN 2048
#define RNN 1024
#define EMB 512
#define ATT 128
#define NF 32
#define KS 31
#define PADK 15
#define CKN 62      // 2*KS
#define ETT 128     // t-tile per fused block
#define NTILE (TN / ETT)   // 16
#define GRP 8       // t's per conv window group (window = 40 floats, 10 b128)

__device__ __forceinline__ float fast_rcp(float x) {
#if __has_builtin(__builtin_amdgcn_rcpf)
    return __builtin_amdgcn_rcpf(x);
#else
    return 1.0f / x;
#endif
}

// tanh(x) = 1 - 2/(exp(2x)+1)
__device__ __forceinline__ float fast_tanh(float x) {
    float s = __expf(2.0f * x);
    return 1.0f - 2.0f * fast_rcp(s + 1.0f);
}

// blocks 0..BB-1: pq[b][a] = dot(hidden[b], Wq[a])
// block BB:       UT[ck][a] = sum_f Wd[a][f] * conv_w[f][ck]  (transposed)
__global__ __launch_bounds__(256) void prep_kernel(
    const float* __restrict__ ahs, const float* __restrict__ Wq,
    const float* __restrict__ conv_w, const float* __restrict__ Wd,
    float* __restrict__ ws_pq, float* __restrict__ ws_UT)
{
    int tid = threadIdx.x;
    if (blockIdx.x < BB) {
        int b = blockIdx.x;
        __shared__ float sh[RNN];
        for (int i = tid; i < RNN; i += 256) sh[i] = ahs[b * RNN + i];
        __syncthreads();
        int a = tid & 127, half = tid >> 7;
        const float4* wq4 = (const float4*)(Wq + a * RNN + half * (RNN / 2));
        const float4* sh4 = (const float4*)(sh + half * (RNN / 2));
        float acc = 0.0f;
#pragma unroll 8
        for (int i = 0; i < RNN / 8; ++i) {
            float4 w4 = wq4[i]; float4 h4 = sh4[i];
            acc = fmaf(w4.x, h4.x, acc);
            acc = fmaf(w4.y, h4.y, acc);
            acc = fmaf(w4.z, h4.z, acc);
            acc = fmaf(w4.w, h4.w, acc);
        }
        __shared__ float part[256];
        part[tid] = acc;
        __syncthreads();
        if (half == 0) ws_pq[b * ATT + a] = part[a] + part[a + 128];
    } else {
        __shared__ float sWd[ATT * NF];
        __shared__ float sCw[NF * CKN];
        for (int i = tid; i < ATT * NF; i += 256) sWd[i] = Wd[i];
        for (int i = tid; i < NF * CKN; i += 256) sCw[i] = conv_w[i];
        __syncthreads();
        for (int idx = tid; idx < ATT * CKN; idx += 256) {
            int a = idx & 127, ck = idx >> 7;
            float acc = 0.0f;
#pragma unroll
            for (int f = 0; f < NF; ++f) acc = fmaf(sWd[a * NF + f], sCw[f * CKN + ck], acc);
            ws_UT[idx] = acc;
        }
    }
}

// grid (BB, NTILE), block 256 = 4 waves. Per block (one 128-t tile of one b):
//   phase A: energies (wave h=w&1 covers a-half, seg=w>>1 covers 64 t's,
//            8-t groups with 40-float windows -> 10 ds_read_b128/channel)
//   phase B: tile softmax stats via shfl (no online rescale)
//   phase C: context stream (128 rows x 512 f), partial + stats to ws.
__global__ __launch_bounds__(256) void fused_kernel(
    const float* __restrict__ awc, const float* __restrict__ pm,
    const float* __restrict__ vvec, const uint8_t* __restrict__ mask,
    const float* __restrict__ mem,
    const float* __restrict__ ws_pq, const float* __restrict__ ws_UT,
    float* __restrict__ ws_e, float* __restrict__ ws_mt,
    float* __restrict__ ws_st, float* __restrict__ ws_cpart)
{
    __shared__ __align__(16) float sA[2][ETT + 40];  // halo 15 each side (fill 0..157)
    __shared__ float sEc[2][ETT];                    // per-a-half partial energies
    __shared__ float sw[ETT];                        // exp(e - m_t)
    __shared__ float sM[2], sS[2];
    __shared__ float4 sacc[128];

    int tid = threadIdx.x;
    int b = blockIdx.x, tile = blockIdx.y, t0 = tile * ETT;

    for (int idx = tid; idx < 2 * (ETT + 30); idx += 256) {
        int c = idx / (ETT + 30), tt = idx % (ETT + 30);
        int t = t0 + tt - PADK;
        sA[c][tt] = (t >= 0 && t < TN) ? awc[(b * 2 + c) * TN + t] : 0.0f;
    }

    int lane = tid & 63, w = tid >> 6;
    int h = w & 1, seg = w >> 1;
    int a = h * 64 + lane;

    float U[CKN];
#pragma unroll
    for (int k = 0; k < CKN; ++k) U[k] = ws_UT[k * ATT + a];   // coalesced
    float q = ws_pq[b * ATT + a];
    float vv = vvec[a];
    const float* pmb = pm + (size_t)b * TN * ATT + a;
    __syncthreads();

    // ---- phase A: energies, 8 groups of 8 t's per wave
    for (int g = 0; g < (ETT / 2) / GRP; ++g) {
        int tl = seg * (ETT / 2) + g * GRP;          // multiple of 8
        const float4* a0 = (const float4*)(&sA[0][tl]);
        const float4* a1 = (const float4*)(&sA[1][tl]);
        float x0[40], x1[40];
#pragma unroll
        for (int j = 0; j < 10; ++j) {               // 20 x ds_read_b128
            float4 r0 = a0[j], r1 = a1[j];
            x0[4 * j] = r0.x; x0[4 * j + 1] = r0.y; x0[4 * j + 2] = r0.z; x0[4 * j + 3] = r0.w;
            x1[4 * j] = r1.x; x1[4 * j + 1] = r1.y; x1[4 * j + 2] = r1.z; x1[4 * j + 3] = r1.w;
        }
        float p[GRP];
#pragma unroll
        for (int u = 0; u < GRP; ++u) p[u] = pmb[(size_t)(t0 + tl + u) * ATT];
#pragma unroll
        for (int u = 0; u < GRP; ++u) {
            float lo = 0.0f;
#pragma unroll
            for (int k = 0; k < KS; ++k) {
                lo = fmaf(U[k],      x0[u + k], lo);
                lo = fmaf(U[KS + k], x1[u + k], lo);
            }
            float e = vv * fast_tanh(q + lo + p[u]);
#pragma unroll
            for (int off = 32; off >= 1; off >>= 1) e += __shfl_xor(e, off, 64);
            if (lane == 0) sEc[h][tl + u] = e;
        }
    }
    __syncthreads();

    // ---- phase B: combine halves, mask, tile max/sum via shfl (waves 0,1)
    float e = 0.0f;
    if (tid < ETT) {
        e = sEc[0][tid] + sEc[1][tid];
        if (mask[(size_t)b * TN + t0 + tid]) e = -1e30f;
        ws_e[(size_t)b * TN + t0 + tid] = e;
        float mloc = e;
#pragma unroll
        for (int off = 32; off >= 1; off >>= 1) mloc = fmaxf(mloc, __shfl_xor(mloc, off, 64));
        if (lane == 0) sM[w] = mloc;
    }
    __syncthreads();
    float m_t = fmaxf(sM[0], sM[1]);
    if (tid < ETT) {
        float wgt = __expf(e - m_t);
        sw[tid] = wgt;
        float sloc = wgt;
#pragma unroll
        for (int off = 32; off >= 1; off >>= 1) sloc += __shfl_xor(sloc, off, 64);
        if (lane == 0) sS[w] = sloc;
    }
    __syncthreads();

    // ---- phase C: context stream, unnormalized partial
    int e4 = tid & 127, sub = tid >> 7;
    const float4* m4 = (const float4*)(mem + (size_t)(b * TN + t0) * EMB);
    float4 acc = make_float4(0.f, 0.f, 0.f, 0.f);
#pragma unroll 4
    for (int i = sub; i < ETT; i += 2) {
        float wt = sw[i];
        float4 mv = m4[(size_t)i * 128 + e4];
        acc.x = fmaf(wt, mv.x, acc.x);
        acc.y = fmaf(wt, mv.y, acc.y);
        acc.z = fmaf(wt, mv.z, acc.z);
        acc.w = fmaf(wt, mv.w, acc.w);
    }
    if (sub == 1) sacc[e4] = acc;
    __syncthreads();
    if (sub == 0) {
        float4 o = sacc[e4];
        acc.x += o.x; acc.y += o.y; acc.z += o.z; acc.w += o.w;
        ((float4*)&ws_cpart[((size_t)tile * BB + b) * EMB])[e4] = acc;
    }
    if (tid == 0) {
        ws_mt[tile * BB + b] = m_t;
        ws_st[tile * BB + b] = sS[0] + sS[1];
    }
}

// grid BB: global (m, S) per row from NTILE tile stats; weights from ws_e.
__global__ __launch_bounds__(256) void weights_kernel(
    const float* __restrict__ ws_e, const float* __restrict__ ws_mt,
    const float* __restrict__ ws_st, float* __restrict__ out_w)
{
    int b = blockIdx.x, tid = threadIdx.x;
    float m = -1e30f;
#pragma unroll
    for (int t = 0; t < NTILE; ++t) m = fmaxf(m, ws_mt[t * BB + b]);
    float S = 0.0f;
#pragma unroll
    for (int t = 0; t < NTILE; ++t) S += ws_st[t * BB + b] * __expf(ws_mt[t * BB + b] - m);
    float inv = 1.0f / S;
#pragma unroll
    for (int i = 0; i < TN / 256; ++i) {
        int t = tid + i * 256;
        out_w[(size_t)b * TN + t] = __expf(ws_e[(size_t)b * TN + t] - m) * inv;
    }
}

// grid (BB*EMB/256): combine tile partials with rescale, normalize.
__global__ __launch_bounds__(256) void ctx_reduce_kernel(
    const float* __restrict__ ws_cpart, const float* __restrict__ ws_mt,
    const float* __restrict__ ws_st, float* __restrict__ out_ctx)
{
    int o = blockIdx.x * 256 + threadIdx.x;
    int b = o >> 9, e = o & 511;
    float m = -1e30f;
#pragma unroll
    for (int t = 0; t < NTILE; ++t) m = fmaxf(m, ws_mt[t * BB + b]);
    float S = 0.0f, acc = 0.0f;
#pragma unroll
    for (int t = 0; t < NTILE; ++t) {
        float f = __expf(ws_mt[t * BB + b] - m);
        S += ws_st[t * BB + b] * f;
        acc += ws_cpart[((size_t)t * BB + b) * EMB + e] * f;
    }
    out_ctx[o] = acc / S;
}

extern "C" void kernel_launch(void* const* d_in, const int* in_sizes, int n_in,
                              void* d_out, int out_size, void* d_ws, size_t ws_size,
                              hipStream_t stream) {
    const float*   ahs  = (const float*)d_in[0];
    const float*   mem  = (const float*)d_in[1];
    const float*   pm   = (const float*)d_in[2];
    const float*   awc  = (const float*)d_in[3];
    const uint8_t* mask = (const uint8_t*)d_in[4];
    const float*   Wq   = (const float*)d_in[5];
    const float*   cw   = (const float*)d_in[6];
    const float*   Wd   = (const float*)d_in[7];
    const float*   v    = (const float*)d_in[8];

    float* out_ctx = (float*)d_out;             // B*EMB
    float* out_w   = (float*)d_out + BB * EMB;  // B*T

    float* ws       = (float*)d_ws;
    float* ws_pq    = ws;             // 8192 floats
    float* ws_UT    = ws + 8192;      // 7936 floats
    float* ws_e     = ws + 16384;     // 131072 floats
    float* ws_mt    = ws + 147456;    // NTILE*BB = 1024 floats
    float* ws_st    = ws + 148480;    // 1024 floats
    float* ws_cpart = ws + 149504;    // NTILE*BB*EMB = 524288 floats

    prep_kernel<<<BB + 1, 256, 0, stream>>>(ahs, Wq, cw, Wd, ws_pq, ws_UT);
    fused_kernel<<<dim3(BB, NTILE), 256, 0, stream>>>(
        awc, pm, v, mask, mem, ws_pq, ws_UT, ws_e, ws_mt, ws_st, ws_cpart);
    weights_kernel<<<BB, 256, 0, stream>>>(ws_e, ws_mt, ws_st, out_w);
    ctx_reduce_kernel<<<(BB * EMB) / 256, 256, 0, stream>>>(ws_cpart, ws_mt, ws_st, out_ctx);
}